// Round 3
// baseline (16.181 us; speedup 1.0000x reference)
//
#include <hip/hip_runtime.h>
#include <hip/hip_bf16.h>

// FastTextItout, MFMA + direct-L2 gather version.
// out[b] = sum_h relu( xw[b,:] @ W[:,h] + S*(lif_b[h]+beta) ) * fc_w[h] + fc_b
// xw[b,:] = sum_t alpha^(63-t) * emb[xis[b,t],:],  S = sum_{k<64} alpha^k.
// B=16384, T=64, EMB=16 (K padded to 32), HID=1024, VOCAB=1001.

#define BB    16384
#define TT    64
#define EMBD  16
#define HIDD  1024
#define ROWS  32            // rows per block
#define NTHR  512           // 8 waves; 16 threads per row
#define NBLK  (BB / ROWS)   // 512 blocks -> 2 blocks/CU
#define XWPAD 24            // shorts per xwb row (48 B: 16B-aligned frags, bank spread)
#define HTPW  8             // h-tiles per wave (8 waves x 8 = 64 tiles = 1024 h)

typedef __attribute__((ext_vector_type(8))) short          frag_ab;
typedef __attribute__((ext_vector_type(4))) float          frag_cd;
typedef __attribute__((ext_vector_type(4))) unsigned short us4;

__device__ __forceinline__ unsigned short f2b(float f) {
    __hip_bfloat16 h = __float2bfloat16(f);   // RNE
    return __builtin_bit_cast(unsigned short, h);
}

__global__ __launch_bounds__(NTHR, 4)   // 4 waves/EU -> 2 blocks/CU, VGPR<=128
void ftt_kernel(const int* __restrict__ xis, const float* __restrict__ emb,
                const float* __restrict__ lif_w, const float* __restrict__ lif_b,
                const float* __restrict__ fc_w, const float* __restrict__ fc_b,
                const float* __restrict__ alpha_p, const float* __restrict__ beta_p,
                float* __restrict__ out)
{
    __shared__ unsigned short xwb[ROWS * XWPAD];    // 1536 B bf16 XW tile
    __shared__ float red[ROWS / 16][8][16];         // 1 KB per-wave partials

    const int tid  = threadIdx.x;
    const int lane = tid & 63;
    const int wave = tid >> 6;
    const int row0 = blockIdx.x * ROWS;
    const float alpha = alpha_p[0];
    const float beta  = beta_p[0];

    // alpha powers via log-squaring; S = (1 - a^64)/(1 - a)
    const float a2  = alpha * alpha;
    const float a4  = a2 * a2;
    const float a8  = a4 * a4;
    const float a16 = a8 * a8;
    const float a32 = a16 * a16;
    const float a48 = a32 * a16;
    const float a64 = a32 * a32;
    const float S   = (fabsf(1.f - alpha) < 1e-8f) ? (float)TT
                                                   : (1.f - a64) / (1.f - alpha);

    // ---- per-wave W fragments / bias / fc_w (bias folded into MFMA C-in)
    const int nn = lane & 15;   // MFMA col within tile
    const int kg = lane >> 4;   // k-group (k = kg*8+i; k>=16 zero pad)

    frag_ab bfrag[HTPW];
    float   biasr[HTPW], fcwr[HTPW];
    #pragma unroll
    for (int j = 0; j < HTPW; ++j) {
        const int h = wave * (HTPW * 16) + j * 16 + nn;
        biasr[j] = S * (lif_b[h] + beta);
        fcwr[j]  = fc_w[h];
        frag_ab b = {0, 0, 0, 0, 0, 0, 0, 0};
        if (kg < 2) {
            #pragma unroll
            for (int i = 0; i < 8; ++i)
                b[i] = (short)f2b(lif_w[(kg * 8 + i) * HIDD + h]);
        }
        bfrag[j] = b;
    }

    // ---- gather: xw[r][:] = sum_t alpha^(63-t) * emb[xis[r][t]][:]
    // 16 threads/row: c = t-chunk (16 t each), q = e-quad (4 elems).
    {
        const int r   = tid >> 4;      // 0..31
        const int sub = tid & 15;
        const int c   = sub >> 2;
        const int q   = sub & 3;
        const int4* xp = (const int4*)(xis + (size_t)(row0 + r) * TT + c * 16);
        const float* eb = emb + q * 4;
        float ax = 0.f, ay = 0.f, az = 0.f, aw = 0.f;
        float w = 1.f;                 // local weight, descending t within chunk
        #pragma unroll
        for (int cc = 3; cc >= 0; --cc) {
            const int4 iv = xp[cc];
            { const float4 e = *(const float4*)(eb + ((size_t)iv.w << 4));
              ax += w * e.x; ay += w * e.y; az += w * e.z; aw += w * e.w; w *= alpha; }
            { const float4 e = *(const float4*)(eb + ((size_t)iv.z << 4));
              ax += w * e.x; ay += w * e.y; az += w * e.z; aw += w * e.w; w *= alpha; }
            { const float4 e = *(const float4*)(eb + ((size_t)iv.y << 4));
              ax += w * e.x; ay += w * e.y; az += w * e.z; aw += w * e.w; w *= alpha; }
            { const float4 e = *(const float4*)(eb + ((size_t)iv.x << 4));
              ax += w * e.x; ay += w * e.y; az += w * e.z; aw += w * e.w; w *= alpha; }
        }
        // chunk c tops out at t=16c+15 whose global weight is alpha^(48-16c)
        const float sc = (c == 3) ? 1.f : ((c == 2) ? a16 : ((c == 1) ? a32 : a48));
        ax *= sc; ay *= sc; az *= sc; aw *= sc;
        // combine 4 chunks (lane bits 2,3)
        ax += __shfl_xor(ax, 4); ay += __shfl_xor(ay, 4);
        az += __shfl_xor(az, 4); aw += __shfl_xor(aw, 4);
        ax += __shfl_xor(ax, 8); ay += __shfl_xor(ay, 8);
        az += __shfl_xor(az, 8); aw += __shfl_xor(aw, 8);
        if (c == 0) {
            us4 u = { f2b(ax), f2b(ay), f2b(az), f2b(aw) };
            *(us4*)&xwb[r * XWPAD + q * 4] = u;
        }
    }
    __syncthreads();   // xwb ready

    // ---- MFMA: 2 row-tiles x 8 h-tiles per wave, fused relu-dot epilogue
    #pragma unroll
    for (int rt = 0; rt < ROWS / 16; ++rt) {
        frag_ab a = {0, 0, 0, 0, 0, 0, 0, 0};
        if (kg < 2)   // real k < 16; kg>=2 lanes stay zero (K padding)
            a = *(const frag_ab*)&xwb[(rt * 16 + nn) * XWPAD + kg * 8];
        frag_cd pacc = {0.f, 0.f, 0.f, 0.f};
        #pragma unroll
        for (int j = 0; j < HTPW; ++j) {
            frag_cd z = { biasr[j], biasr[j], biasr[j], biasr[j] };  // bias as C-in
            frag_cd c = __builtin_amdgcn_mfma_f32_16x16x32_bf16(a, bfrag[j], z, 0, 0, 0);
            #pragma unroll
            for (int x = 0; x < 4; ++x)
                pacc[x] += fmaxf(c[x], 0.f) * fcwr[j];
        }
        // reduce over the 16 n-lanes (masks stay within the kg group)
        #pragma unroll
        for (int m = 1; m <= 8; m <<= 1) {
            #pragma unroll
            for (int x = 0; x < 4; ++x) pacc[x] += __shfl_xor(pacc[x], m);
        }
        if (nn == 0) {
            #pragma unroll
            for (int x = 0; x < 4; ++x)
                red[rt][wave][kg * 4 + x] = pacc[x];   // row m = kg*4+x
        }
    }
    __syncthreads();

    if (tid < ROWS) {
        float s = fc_b[0];
        #pragma unroll
        for (int w2 = 0; w2 < 8; ++w2) s += red[tid >> 4][w2][tid & 15];
        out[row0 + tid] = s;
    }
}

extern "C" void kernel_launch(void* const* d_in, const int* in_sizes, int n_in,
                              void* d_out, int out_size, void* d_ws, size_t ws_size,
                              hipStream_t stream) {
    const int*   xis   = (const int*)d_in[0];
    const float* emb   = (const float*)d_in[1];
    const float* lif_w = (const float*)d_in[2];
    const float* lif_b = (const float*)d_in[3];
    const float* fc_w  = (const float*)d_in[4];
    const float* fc_b  = (const float*)d_in[5];
    const float* alpha = (const float*)d_in[6];
    const float* beta  = (const float*)d_in[7];
    float* out = (float*)d_out;

    ftt_kernel<<<NBLK, NTHR, 0, stream>>>(
        xis, emb, lif_w, lif_b, fc_w, fc_b, alpha, beta, out);
}